// Round 3
// baseline (331.130 us; speedup 1.0000x reference)
//
#include <hip/hip_runtime.h>
#include <hip/hip_bf16.h>

typedef __bf16 bf16;
typedef __bf16 bf16x8 __attribute__((ext_vector_type(8)));
typedef __bf16 bf16x4 __attribute__((ext_vector_type(4)));
typedef float f32x4 __attribute__((ext_vector_type(4)));

#define HIDDEN 2048
#define SEQ 2048
#define NH 16
#define QL 1536
#define KVL 512
// 1/sqrt(192) * log2(e)
#define SCALE_LOG2E 0.10411754631f

// ---- global -> LDS direct load, 16B per lane. Dest = uniform base + lane*16. ----
__device__ __forceinline__ void gload_lds16(const void* g, void* l) {
  typedef const __attribute__((address_space(1))) void* gp_t;
  typedef __attribute__((address_space(3))) void* lp_t;
  __builtin_amdgcn_global_load_lds((gp_t)(unsigned long long)g,
                                   (lp_t)(unsigned int)(unsigned long long)l, 16, 0, 0);
}

// raw v_exp_f32: computes 2^x (1-ulp, handles -inf -> 0)
__device__ __forceinline__ float fexp2(float x) {
  float r; asm("v_exp_f32 %0, %1" : "=v"(r) : "v"(x)); return r;
}

// ================= prep: 5 weight transposes (fp32[K][N] -> bf16[N][K]) + hidden cvt =================
// block ranges: [0,3072) Wqa 48x64 | [3072,7680) Wqb 96x48 | [7680,8832) Wkva 18x64
//               [8832,10880) Wkvb 128x16 | [10880,14976) Wo 64x64 | [14976,19072) cvt
__global__ void k_prep(const float* __restrict__ hidden, bf16* __restrict__ Xb,
                       const float* __restrict__ Wqa, bf16* __restrict__ WqaT,
                       const float* __restrict__ Wqb, bf16* __restrict__ WqbT,
                       const float* __restrict__ Wkva, bf16* __restrict__ WkvaT,
                       const float* __restrict__ Wkvb, bf16* __restrict__ WkvbT,
                       const float* __restrict__ Wo, bf16* __restrict__ WoT) {
  __shared__ float tile[32][33];
  int b = blockIdx.x, tid = threadIdx.x;
  const float* W; bf16* Wt; int K, N, bx, by;
  if (b < 3072)       { W = Wqa;  Wt = WqaT;  K = 2048; N = 1536; int r = b;         bx = r % 48;  by = r / 48; }
  else if (b < 7680)  { W = Wqb;  Wt = WqbT;  K = 1536; N = 3072; int r = b - 3072;  bx = r % 96;  by = r / 96; }
  else if (b < 8832)  { W = Wkva; Wt = WkvaT; K = 2048; N = 576;  int r = b - 7680;  bx = r % 18;  by = r / 18; }
  else if (b < 10880) { W = Wkvb; Wt = WkvbT; K = 512;  N = 4096; int r = b - 8832;  bx = r % 128; by = r / 128; }
  else if (b < 14976) { W = Wo;   Wt = WoT;   K = 2048; N = 2048; int r = b - 10880; bx = r % 64;  by = r / 64; }
  else {
    int r = b - 14976;
    int base = (r * 256 + tid) * 4;
    float4 v = *(const float4*)(hidden + base);
    bf16x4 o = { (bf16)v.x, (bf16)v.y, (bf16)v.z, (bf16)v.w };
    *(bf16x4*)(Xb + base) = o;
    return;
  }
  int n0 = bx * 32, k0 = by * 32, cc = tid & 31, rr = tid >> 5;
#pragma unroll
  for (int it = 0; it < 4; ++it) {
    int r = it * 8 + rr;
    tile[r][cc] = W[(size_t)(k0 + r) * N + n0 + cc];
  }
  __syncthreads();
#pragma unroll
  for (int it = 0; it < 4; ++it) {
    int r = it * 8 + rr;
    Wt[(size_t)(n0 + r) * K + k0 + cc] = (bf16)tile[cc][r];
  }
}

// ================= GEMM body (m97 structure): C[M][N] = A[M][K] @ Bt[N][K]^T =================
__device__ __forceinline__ void gemm_body(const bf16* __restrict__ A, const bf16* __restrict__ Bt,
                                          bf16* __restrict__ Cb, float* __restrict__ Cf,
                                          int N, int K, int m0, int n0, bf16* As, bf16* Bs) {
  int tid = threadIdx.x, lane = tid & 63, w = tid >> 6;
  int wr = w >> 1, wc = w & 1;
  int l15 = lane & 15, l4 = lane >> 4;
  f32x4 acc[4][4] = {};
  for (int k0 = 0; k0 < K; k0 += 64) {
#pragma unroll
    for (int i = 0; i < 4; ++i) {
      int c = w * 4 + i;
      int row = c * 8 + (lane >> 3);
      int col = (lane & 7) * 8;
      gload_lds16(&A[(size_t)(m0 + row) * K + k0 + col], &As[c * 512]);
      gload_lds16(&Bt[(size_t)(n0 + row) * K + k0 + col], &Bs[c * 512]);
    }
    __syncthreads();
#pragma unroll
    for (int kk = 0; kk < 2; ++kk) {
      bf16x8 af[4], bfr[4];
#pragma unroll
      for (int m = 0; m < 4; ++m)
        af[m] = *(const bf16x8*)&As[(wr * 64 + m * 16 + l15) * 64 + kk * 32 + l4 * 8];
#pragma unroll
      for (int n = 0; n < 4; ++n)
        bfr[n] = *(const bf16x8*)&Bs[(wc * 64 + n * 16 + l15) * 64 + kk * 32 + l4 * 8];
      __builtin_amdgcn_s_setprio(1);
#pragma unroll
      for (int m = 0; m < 4; ++m)
#pragma unroll
        for (int n = 0; n < 4; ++n)
          acc[m][n] = __builtin_amdgcn_mfma_f32_16x16x32_bf16(af[m], bfr[n], acc[m][n], 0, 0, 0);
      __builtin_amdgcn_s_setprio(0);
    }
    __syncthreads();
  }
#pragma unroll
  for (int m = 0; m < 4; ++m)
#pragma unroll
    for (int n = 0; n < 4; ++n)
#pragma unroll
      for (int r = 0; r < 4; ++r) {
        int grow = m0 + wr * 64 + m * 16 + l4 * 4 + r;
        int gcol = n0 + wc * 64 + n * 16 + l15;
        if (gcol < N) {
          float v = acc[m][n][r];
          if (Cf) Cf[(size_t)grow * N + gcol] = v;
          else Cb[(size_t)grow * N + gcol] = (bf16)v;
        }
      }
}

// generic GEMM (Wo)
__global__ __launch_bounds__(256) void k_gemm(const bf16* __restrict__ A, const bf16* __restrict__ Bt,
                                              bf16* __restrict__ Cb, float* __restrict__ Cf,
                                              int N, int K) {
  __shared__ __align__(16) bf16 As[128 * 64];
  __shared__ __align__(16) bf16 Bs[128 * 64];
  gemm_body(A, Bt, Cb, Cf, N, K, blockIdx.x * 128, blockIdx.y * 128, As, Bs);
}

// dual GEMM A: Xb @ {WqaT -> qa (N=1536) | WkvaT -> kvc (N=576)}, K=2048
__global__ __launch_bounds__(256) void k_gemm_a(const bf16* __restrict__ Xb,
                                                const bf16* __restrict__ B1, const bf16* __restrict__ B2,
                                                float* __restrict__ C1, float* __restrict__ C2) {
  __shared__ __align__(16) bf16 As[128 * 64];
  __shared__ __align__(16) bf16 Bs[128 * 64];
  int by = blockIdx.y;
  if (by < 12) gemm_body(Xb, B1, nullptr, C1, 1536, 2048, blockIdx.x * 128, by * 128, As, Bs);
  else         gemm_body(Xb, B2, nullptr, C2, 576, 2048, blockIdx.x * 128, (by - 12) * 128, As, Bs);
}

// dual GEMM B: {qc @ WqbT -> Qm (N=3072,K=1536) | kvn @ WkvbT -> KVm (N=4096,K=512)}
__global__ __launch_bounds__(256) void k_gemm_b(const bf16* __restrict__ A1, const bf16* __restrict__ A2,
                                                const bf16* __restrict__ B1, const bf16* __restrict__ B2,
                                                bf16* __restrict__ C1, bf16* __restrict__ C2) {
  __shared__ __align__(16) bf16 As[128 * 64];
  __shared__ __align__(16) bf16 Bs[128 * 64];
  int by = blockIdx.y;
  if (by < 24) gemm_body(A1, B1, C1, nullptr, 3072, 1536, blockIdx.x * 128, by * 128, As, Bs);
  else         gemm_body(A2, B2, C2, nullptr, 4096, 512, blockIdx.x * 128, (by - 24) * 128, As, Bs);
}

// ================= merged RMSNorms =================
__device__ inline float block_reduce_sum(float v, float* red) {
#pragma unroll
  for (int off = 1; off < 64; off <<= 1) v += __shfl_xor(v, off);
  int w = threadIdx.x >> 6;
  if ((threadIdx.x & 63) == 0) red[w] = v;
  __syncthreads();
  return red[0] + red[1] + red[2] + red[3];
}

__global__ void k_rms_all(const float* __restrict__ qa, const float* __restrict__ gq, bf16* __restrict__ qc,
                          const float* __restrict__ kvc, const float* __restrict__ gkv,
                          bf16* __restrict__ kvn, bf16* __restrict__ kr) {
  __shared__ float red[4];
  int b = blockIdx.x, tid = threadIdx.x;
  if (b < 2048) {
    int row = b;
    float v[6];
    float ss = 0.f;
#pragma unroll
    for (int j = 0; j < 6; ++j) {
      v[j] = qa[(size_t)row * QL + tid + j * 256];
      ss += v[j] * v[j];
    }
    float tot = block_reduce_sum(ss, red);
    float rs = rsqrtf(tot / (float)QL + 1e-6f);
#pragma unroll
    for (int j = 0; j < 6; ++j) {
      int c = tid + j * 256;
      qc[(size_t)row * QL + c] = (bf16)(v[j] * rs * gq[c]);
    }
  } else {
    int row = b - 2048;
    float v0 = kvc[(size_t)row * 576 + tid];
    float v1 = kvc[(size_t)row * 576 + tid + 256];
    float tot = block_reduce_sum(v0 * v0 + v1 * v1, red);
    float rs = rsqrtf(tot / (float)KVL + 1e-6f);
    kvn[(size_t)row * KVL + tid] = (bf16)(v0 * rs * gkv[tid]);
    kvn[(size_t)row * KVL + tid + 256] = (bf16)(v1 * rs * gkv[tid + 256]);
    if (tid < 64) kr[row * 64 + tid] = (bf16)kvc[(size_t)row * 576 + 512 + tid];
  }
}

// ================= V global transpose: VT[h][d][s] = KVm[s][h*256+128+d] =================
// grid 4096 = 16h x 4 dblk x 64 sblk
__global__ void k_vt(const bf16* __restrict__ KVm, bf16* __restrict__ VT) {
  __shared__ bf16 tile[32][34];
  int b = blockIdx.x, tid = threadIdx.x;
  int h = b >> 8, rem = b & 255;
  int d0 = (rem >> 6) * 32, s0 = (rem & 63) * 32;
  int cc = tid & 31, rr = tid >> 5;
#pragma unroll
  for (int it = 0; it < 4; ++it) {
    int r = it * 8 + rr;  // s-local
    tile[r][cc] = KVm[(size_t)(s0 + r) * 4096 + h * 256 + 128 + d0 + cc];
  }
  __syncthreads();
#pragma unroll
  for (int it = 0; it < 4; ++it) {
    int r = it * 8 + rr;  // d-local
    VT[((size_t)(h * 128 + d0 + r)) * 2048 + s0 + cc] = tile[cc][r];
  }
}

// ================= fused causal flash attention =================
// grid 512: h = bid&15, qb balanced pairing. 4 waves x 16 q-rows, KVBLK=64.
// LDS 52KB -> 3 blocks/CU. 2 barriers/tile. lsum via ones-column MFMA. defer-max.
__global__ __launch_bounds__(256, 3) void k_attn(const bf16* __restrict__ Q, const bf16* __restrict__ KV,
                                                 const bf16* __restrict__ KR, const bf16* __restrict__ VT,
                                                 bf16* __restrict__ O) {
  __shared__ __align__(16) bf16 Ks[64 * 200];     // [kvpos][192+8]  25.0KB
  __shared__ __align__(16) bf16 Vt[128 * 72];     // [feat][64+8]    18.0KB
  __shared__ __align__(16) bf16 Ps[4 * 16 * 72];  // per-wave P       9.0KB
  int bid = blockIdx.x;
  int h = bid & 15, i = bid >> 4;
  int qb = (i < 16) ? i : 47 - i;
  int q0 = qb * 64;
  int tid = threadIdx.x, lane = tid & 63, w = tid >> 6;
  int l15 = lane & 15, l4 = lane >> 4;
  bf16* Pw = Ps + w * 16 * 72;
  const bf16* VTh = VT + (size_t)h * 128 * 2048;

  // Q fragments in registers
  bf16x8 aq[6];
  int qrow = q0 + w * 16 + l15;
#pragma unroll
  for (int ks = 0; ks < 6; ++ks)
    aq[ks] = *(const bf16x8*)&Q[(size_t)qrow * 3072 + h * 192 + ks * 32 + l4 * 8];

  // constant ones B-fragment (row n=0 of B = ones) for lsum-via-MFMA
  bf16x8 ones_b;
  {
    float ov = (l15 == 0) ? 1.0f : 0.0f;
#pragma unroll
    for (int j = 0; j < 8; ++j) ones_b[j] = (bf16)ov;
  }

  f32x4 oacc[8] = {};
  f32x4 o9 = {0.f, 0.f, 0.f, 0.f};  // running lsum per row (col 0 of ones-MFMA)
  float m[4] = {-1e30f, -1e30f, -1e30f, -1e30f};
  int nt = qb + 1;
  for (int t = 0; t < nt; ++t) {
    // stage K tile [64][192]: cols 0..127 = k_nope, 128..191 = k_rope
#pragma unroll
    for (int it = 0; it < 6; ++it) {
      int idx = it * 256 + tid;
      int r = idx / 24, gg = idx % 24;
      int p = t * 64 + r;
      int4 val;
      if (gg < 16) val = *(const int4*)&KV[(size_t)p * 4096 + h * 256 + gg * 8];
      else         val = *(const int4*)&KR[(size_t)p * 64 + (gg - 16) * 8];
      *(int4*)&Ks[r * 200 + gg * 8] = val;
    }
    // stage V^T tile [128 d][64 k] from VT (coalesced, vectorized)
#pragma unroll
    for (int it = 0; it < 4; ++it) {
      int idx = it * 256 + tid;
      int d = idx >> 3, c = idx & 7;
      *(int4*)&Vt[d * 72 + c * 8] = *(const int4*)&VTh[(size_t)d * 2048 + t * 64 + c * 8];
    }
    __syncthreads();  // A: tiles ready

    // S = Q @ K^T : 16x64 per wave
    f32x4 sacc[4] = {};
    __builtin_amdgcn_s_setprio(1);
#pragma unroll
    for (int ks = 0; ks < 6; ++ks)
#pragma unroll
      for (int n = 0; n < 4; ++n) {
        bf16x8 bk = *(const bf16x8*)&Ks[(n * 16 + l15) * 200 + ks * 32 + l4 * 8];
        sacc[n] = __builtin_amdgcn_mfma_f32_16x16x32_bf16(aq[ks], bk, sacc[n], 0, 0, 0);
      }
    __builtin_amdgcn_s_setprio(0);

    // scale (log2 domain) + causal mask (diagonal tile only)
    bool lastt = (t == nt - 1);
#pragma unroll
    for (int n = 0; n < 4; ++n)
#pragma unroll
      for (int r = 0; r < 4; ++r) {
        float v = sacc[n][r] * SCALE_LOG2E;
        if (lastt) {
          int col = t * 64 + n * 16 + l15;
          int rowg = q0 + w * 16 + l4 * 4 + r;
          if (col > rowg) v = -1e30f;
        }
        sacc[n][r] = v;
      }

    // row max
    float pmax[4];
#pragma unroll
    for (int r = 0; r < 4; ++r) {
      float mx = fmaxf(fmaxf(sacc[0][r], sacc[1][r]), fmaxf(sacc[2][r], sacc[3][r]));
      mx = fmaxf(mx, __shfl_xor(mx, 1));
      mx = fmaxf(mx, __shfl_xor(mx, 2));
      mx = fmaxf(mx, __shfl_xor(mx, 4));
      mx = fmaxf(mx, __shfl_xor(mx, 8));
      pmax[r] = mx;
    }
    // defer-max (T13): only rescale when the max moved by > 8 (in log2 domain)
    float need = 0.f;
#pragma unroll
    for (int r = 0; r < 4; ++r) need = fmaxf(need, pmax[r] - m[r]);
    if (__any(need > 8.0f)) {
#pragma unroll
      for (int r = 0; r < 4; ++r) {
        float mn = fmaxf(m[r], pmax[r]);
        float al = fexp2(m[r] - mn);
        m[r] = mn;
#pragma unroll
        for (int vf = 0; vf < 8; ++vf) oacc[vf][r] *= al;
        o9[r] *= al;
      }
    }

    // P = exp2(S - m) -> bf16 -> per-wave LDS
#pragma unroll
    for (int n = 0; n < 4; ++n)
#pragma unroll
      for (int r = 0; r < 4; ++r)
        Pw[(l4 * 4 + r) * 72 + n * 16 + l15] = (bf16)fexp2(sacc[n][r] - m[r]);

    // PV + lsum MFMAs (Pw is wave-private; Vt staged pre-barrier-A -> no barrier needed)
    __builtin_amdgcn_s_setprio(1);
#pragma unroll
    for (int ks = 0; ks < 2; ++ks) {
      bf16x8 ap = *(const bf16x8*)&Pw[l15 * 72 + ks * 32 + l4 * 8];
      o9 = __builtin_amdgcn_mfma_f32_16x16x32_bf16(ap, ones_b, o9, 0, 0, 0);
#pragma unroll
      for (int vf = 0; vf < 8; ++vf) {
        bf16x8 bv = *(const bf16x8*)&Vt[(vf * 16 + l15) * 72 + ks * 32 + l4 * 8];
        oacc[vf] = __builtin_amdgcn_mfma_f32_16x16x32_bf16(ap, bv, oacc[vf], 0, 0, 0);
      }
    }
    __builtin_amdgcn_s_setprio(0);
    __syncthreads();  // C: PV done -> next stage may overwrite Ks/Vt
  }

  // epilogue: lsum broadcast from col-0 lanes, normalize, store
#pragma unroll
  for (int r = 0; r < 4; ++r) {
    float ls = __shfl(o9[r], lane & 48);
    float inv = 1.0f / ls;
#pragma unroll
    for (int vf = 0; vf < 8; ++vf) {
      int rowg = q0 + w * 16 + l4 * 4 + r;
      int col = h * 128 + vf * 16 + l15;
      O[(size_t)rowg * 2048 + col] = (bf16)(oacc[vf][r] * inv);
    }
  }
}

extern "C" void kernel_launch(void* const* d_in, const int* in_sizes, int n_in,
                              void* d_out, int out_size, void* d_ws, size_t ws_size,
                              hipStream_t stream) {
  (void)in_sizes; (void)n_in; (void)out_size; (void)ws_size;
  const float* hidden = (const float*)d_in[0];
  const float* Wqa  = (const float*)d_in[2];
  const float* gqa  = (const float*)d_in[3];
  const float* Wqb  = (const float*)d_in[4];
  const float* Wkva = (const float*)d_in[5];
  const float* gkva = (const float*)d_in[6];
  const float* Wkvb = (const float*)d_in[7];
  const float* Wo   = (const float*)d_in[8];
  float* out = (float*)d_out;

  char* ws = (char*)d_ws;
  size_t off = 0;
  auto alloc = [&](size_t bytes) {
    char* p = ws + off;
    off += (bytes + 255) & ~(size_t)255;
    return p;
  };
  bf16* Xb     = (bf16*)alloc((size_t)SEQ * HIDDEN * 2);
  bf16* WqaT   = (bf16*)alloc((size_t)QL * HIDDEN * 2);
  bf16* WqbT   = (bf16*)alloc((size_t)3072 * QL * 2);
  bf16* WkvaT  = (bf16*)alloc((size_t)576 * HIDDEN * 2);
  bf16* WkvbT  = (bf16*)alloc((size_t)4096 * KVL * 2);
  bf16* WoT    = (bf16*)alloc((size_t)2048 * 2048 * 2);
  float* qa    = (float*)alloc((size_t)SEQ * QL * 4);
  float* kvc   = (float*)alloc((size_t)SEQ * 576 * 4);
  bf16* qc     = (bf16*)alloc((size_t)SEQ * QL * 2);
  bf16* kvn    = (bf16*)alloc((size_t)SEQ * KVL * 2);
  bf16* krope  = (bf16*)alloc((size_t)SEQ * 64 * 2);
  bf16* Qm     = (bf16*)alloc((size_t)SEQ * 3072 * 2);
  bf16* KVm    = (bf16*)alloc((size_t)SEQ * 4096 * 2);
  bf16* VTg    = (bf16*)alloc((size_t)NH * 128 * SEQ * 2);
  bf16* Om     = (bf16*)alloc((size_t)SEQ * 2048 * 2);

  // 1. all weight transposes + hidden cvt (one launch)
  k_prep<<<19072, 256, 0, stream>>>(hidden, Xb, Wqa, WqaT, Wqb, WqbT,
                                    Wkva, WkvaT, Wkvb, WkvbT, Wo, WoT);
  // 2. LoRA-A projections (merged)
  k_gemm_a<<<dim3(16, 17), 256, 0, stream>>>(Xb, WqaT, WkvaT, qa, kvc);
  // 3. RMSNorms (merged)
  k_rms_all<<<4096, 256, 0, stream>>>(qa, gqa, qc, kvc, gkva, kvn, krope);
  // 4. LoRA-B projections (merged)
  k_gemm_b<<<dim3(16, 56), 256, 0, stream>>>(qc, kvn, WqbT, WkvbT, Qm, KVm);
  // 5. V global transpose
  k_vt<<<4096, 256, 0, stream>>>(KVm, VTg);
  // 6. fused causal attention
  k_attn<<<512, 256, 0, stream>>>(Qm, KVm, krope, VTg, Om);
  // 7. output projection -> fp32 d_out
  k_gemm<<<dim3(16, 16), 256, 0, stream>>>(Om, WoT, nullptr, out, 2048, 2048);
}

// Round 4
// 244.627 us; speedup vs baseline: 1.3536x; 1.3536x over previous
//
#include <hip/hip_runtime.h>
#include <hip/hip_bf16.h>

typedef __bf16 bf16;
typedef __bf16 bf16x8 __attribute__((ext_vector_type(8)));
typedef __bf16 bf16x4 __attribute__((ext_vector_type(4)));
typedef float f32x4 __attribute__((ext_vector_type(4)));

#define HIDDEN 2048
#define SEQ 2048
#define NH 16
#define QL 1536
#define KVL 512
// 1/sqrt(192) * log2(e)
#define SCALE_LOG2E 0.10411754631f

// ---- global -> LDS direct load, 16B per lane. Dest = uniform base + lane*16. ----
__device__ __forceinline__ void gload_lds16(const void* g, void* l) {
  typedef const __attribute__((address_space(1))) void* gp_t;
  typedef __attribute__((address_space(3))) void* lp_t;
  __builtin_amdgcn_global_load_lds((gp_t)(unsigned long long)g,
                                   (lp_t)(unsigned int)(unsigned long long)l, 16, 0, 0);
}

// raw v_exp_f32: computes 2^x (1-ulp, handles -inf -> 0)
__device__ __forceinline__ float fexp2(float x) {
  float r; asm("v_exp_f32 %0, %1" : "=v"(r) : "v"(x)); return r;
}

// ================= prep: 5 weight transposes (fp32[K][N] -> bf16[N][K]) + hidden cvt =================
__global__ void k_prep(const float* __restrict__ hidden, bf16* __restrict__ Xb,
                       const float* __restrict__ Wqa, bf16* __restrict__ WqaT,
                       const float* __restrict__ Wqb, bf16* __restrict__ WqbT,
                       const float* __restrict__ Wkva, bf16* __restrict__ WkvaT,
                       const float* __restrict__ Wkvb, bf16* __restrict__ WkvbT,
                       const float* __restrict__ Wo, bf16* __restrict__ WoT) {
  __shared__ float tile[32][33];
  int b = blockIdx.x, tid = threadIdx.x;
  const float* W; bf16* Wt; int K, N, bx, by;
  if (b < 3072)       { W = Wqa;  Wt = WqaT;  K = 2048; N = 1536; int r = b;         bx = r % 48;  by = r / 48; }
  else if (b < 7680)  { W = Wqb;  Wt = WqbT;  K = 1536; N = 3072; int r = b - 3072;  bx = r % 96;  by = r / 96; }
  else if (b < 8832)  { W = Wkva; Wt = WkvaT; K = 2048; N = 576;  int r = b - 7680;  bx = r % 18;  by = r / 18; }
  else if (b < 10880) { W = Wkvb; Wt = WkvbT; K = 512;  N = 4096; int r = b - 8832;  bx = r % 128; by = r / 128; }
  else if (b < 14976) { W = Wo;   Wt = WoT;   K = 2048; N = 2048; int r = b - 10880; bx = r % 64;  by = r / 64; }
  else {
    int r = b - 14976;
    int base = (r * 256 + tid) * 4;
    float4 v = *(const float4*)(hidden + base);
    bf16x4 o = { (bf16)v.x, (bf16)v.y, (bf16)v.z, (bf16)v.w };
    *(bf16x4*)(Xb + base) = o;
    return;
  }
  int n0 = bx * 32, k0 = by * 32, cc = tid & 31, rr = tid >> 5;
#pragma unroll
  for (int it = 0; it < 4; ++it) {
    int r = it * 8 + rr;
    tile[r][cc] = W[(size_t)(k0 + r) * N + n0 + cc];
  }
  __syncthreads();
#pragma unroll
  for (int it = 0; it < 4; ++it) {
    int r = it * 8 + rr;
    Wt[(size_t)(n0 + r) * K + k0 + cc] = (bf16)tile[cc][r];
  }
}

// ================= GEMM body (m97 structure): C[M][N] = A[M][K] @ Bt[N][K]^T =================
__device__ __forceinline__ void gemm_body(const bf16* __restrict__ A, const bf16* __restrict__ Bt,
                                          bf16* __restrict__ Cb, float* __restrict__ Cf,
                                          int N, int K, int m0, int n0, bf16* As, bf16* Bs) {
  int tid = threadIdx.x, lane = tid & 63, w = tid >> 6;
  int wr = w >> 1, wc = w & 1;
  int l15 = lane & 15, l4 = lane >> 4;
  f32x4 acc[4][4] = {};
  for (int k0 = 0; k0 < K; k0 += 64) {
#pragma unroll
    for (int i = 0; i < 4; ++i) {
      int c = w * 4 + i;
      int row = c * 8 + (lane >> 3);
      int col = (lane & 7) * 8;
      gload_lds16(&A[(size_t)(m0 + row) * K + k0 + col], &As[c * 512]);
      gload_lds16(&Bt[(size_t)(n0 + row) * K + k0 + col], &Bs[c * 512]);
    }
    __syncthreads();
#pragma unroll
    for (int kk = 0; kk < 2; ++kk) {
      bf16x8 af[4], bfr[4];
#pragma unroll
      for (int m = 0; m < 4; ++m)
        af[m] = *(const bf16x8*)&As[(wr * 64 + m * 16 + l15) * 64 + kk * 32 + l4 * 8];
#pragma unroll
      for (int n = 0; n < 4; ++n)
        bfr[n] = *(const bf16x8*)&Bs[(wc * 64 + n * 16 + l15) * 64 + kk * 32 + l4 * 8];
      __builtin_amdgcn_s_setprio(1);
#pragma unroll
      for (int m = 0; m < 4; ++m)
#pragma unroll
        for (int n = 0; n < 4; ++n)
          acc[m][n] = __builtin_amdgcn_mfma_f32_16x16x32_bf16(af[m], bfr[n], acc[m][n], 0, 0, 0);
      __builtin_amdgcn_s_setprio(0);
    }
    __syncthreads();
  }
#pragma unroll
  for (int m = 0; m < 4; ++m)
#pragma unroll
    for (int n = 0; n < 4; ++n)
#pragma unroll
      for (int r = 0; r < 4; ++r) {
        int grow = m0 + wr * 64 + m * 16 + l4 * 4 + r;
        int gcol = n0 + wc * 64 + n * 16 + l15;
        if (gcol < N) {
          float v = acc[m][n][r];
          if (Cf) Cf[(size_t)grow * N + gcol] = v;
          else Cb[(size_t)grow * N + gcol] = (bf16)v;
        }
      }
}

// generic GEMM (Wo)
__global__ __launch_bounds__(256) void k_gemm(const bf16* __restrict__ A, const bf16* __restrict__ Bt,
                                              bf16* __restrict__ Cb, float* __restrict__ Cf,
                                              int N, int K) {
  __shared__ __align__(16) bf16 As[128 * 64];
  __shared__ __align__(16) bf16 Bs[128 * 64];
  gemm_body(A, Bt, Cb, Cf, N, K, blockIdx.x * 128, blockIdx.y * 128, As, Bs);
}

// dual GEMM A: Xb @ {WqaT -> qa (N=1536) | WkvaT -> kvc (N=576)}, K=2048
__global__ __launch_bounds__(256) void k_gemm_a(const bf16* __restrict__ Xb,
                                                const bf16* __restrict__ B1, const bf16* __restrict__ B2,
                                                float* __restrict__ C1, float* __restrict__ C2) {
  __shared__ __align__(16) bf16 As[128 * 64];
  __shared__ __align__(16) bf16 Bs[128 * 64];
  int by = blockIdx.y;
  if (by < 12) gemm_body(Xb, B1, nullptr, C1, 1536, 2048, blockIdx.x * 128, by * 128, As, Bs);
  else         gemm_body(Xb, B2, nullptr, C2, 576, 2048, blockIdx.x * 128, (by - 12) * 128, As, Bs);
}

// dual GEMM B: {qc @ WqbT -> Qm (N=3072,K=1536) | kvn @ WkvbT -> KVm (N=4096,K=512)}
__global__ __launch_bounds__(256) void k_gemm_b(const bf16* __restrict__ A1, const bf16* __restrict__ A2,
                                                const bf16* __restrict__ B1, const bf16* __restrict__ B2,
                                                bf16* __restrict__ C1, bf16* __restrict__ C2) {
  __shared__ __align__(16) bf16 As[128 * 64];
  __shared__ __align__(16) bf16 Bs[128 * 64];
  int by = blockIdx.y;
  if (by < 24) gemm_body(A1, B1, C1, nullptr, 3072, 1536, blockIdx.x * 128, by * 128, As, Bs);
  else         gemm_body(A2, B2, C2, nullptr, 4096, 512, blockIdx.x * 128, (by - 24) * 128, As, Bs);
}

// ================= merged RMSNorms =================
__device__ inline float block_reduce_sum(float v, float* red) {
#pragma unroll
  for (int off = 1; off < 64; off <<= 1) v += __shfl_xor(v, off);
  int w = threadIdx.x >> 6;
  if ((threadIdx.x & 63) == 0) red[w] = v;
  __syncthreads();
  return red[0] + red[1] + red[2] + red[3];
}

__global__ void k_rms_all(const float* __restrict__ qa, const float* __restrict__ gq, bf16* __restrict__ qc,
                          const float* __restrict__ kvc, const float* __restrict__ gkv,
                          bf16* __restrict__ kvn, bf16* __restrict__ kr) {
  __shared__ float red[4];
  int b = blockIdx.x, tid = threadIdx.x;
  if (b < 2048) {
    int row = b;
    float v[6];
    float ss = 0.f;
#pragma unroll
    for (int j = 0; j < 6; ++j) {
      v[j] = qa[(size_t)row * QL + tid + j * 256];
      ss += v[j] * v[j];
    }
    float tot = block_reduce_sum(ss, red);
    float rs = rsqrtf(tot / (float)QL + 1e-6f);
#pragma unroll
    for (int j = 0; j < 6; ++j) {
      int c = tid + j * 256;
      qc[(size_t)row * QL + c] = (bf16)(v[j] * rs * gq[c]);
    }
  } else {
    int row = b - 2048;
    float v0 = kvc[(size_t)row * 576 + tid];
    float v1 = kvc[(size_t)row * 576 + tid + 256];
    float tot = block_reduce_sum(v0 * v0 + v1 * v1, red);
    float rs = rsqrtf(tot / (float)KVL + 1e-6f);
    kvn[(size_t)row * KVL + tid] = (bf16)(v0 * rs * gkv[tid]);
    kvn[(size_t)row * KVL + tid + 256] = (bf16)(v1 * rs * gkv[tid + 256]);
    if (tid < 64) kr[row * 64 + tid] = (bf16)kvc[(size_t)row * 576 + 512 + tid];
  }
}

// ================= V global transpose: VT[h][d][s] = KVm[s][h*256+128+d] =================
__global__ void k_vt(const bf16* __restrict__ KVm, bf16* __restrict__ VT) {
  __shared__ bf16 tile[32][34];
  int b = blockIdx.x, tid = threadIdx.x;
  int h = b >> 8, rem = b & 255;
  int d0 = (rem >> 6) * 32, s0 = (rem & 63) * 32;
  int cc = tid & 31, rr = tid >> 5;
#pragma unroll
  for (int it = 0; it < 4; ++it) {
    int r = it * 8 + rr;  // s-local
    tile[r][cc] = KVm[(size_t)(s0 + r) * 4096 + h * 256 + 128 + d0 + cc];
  }
  __syncthreads();
#pragma unroll
  for (int it = 0; it < 4; ++it) {
    int r = it * 8 + rr;  // d-local
    VT[((size_t)(h * 128 + d0 + r)) * 2048 + s0 + cc] = tile[cc][r];
  }
}

// ================= fused causal flash attention =================
// grid 512: h = bid&15, qb balanced pairing. 4 waves x 16 q-rows, KVBLK=64.
// LDS 52KB -> 3 blocks/CU (VGPR unconstrained: forcing min-waves=3 in R3 caused
// an 80-VGPR squeeze -> scratch spills -> 171us. Plain bounds: LDS caps occupancy.)
__global__ __launch_bounds__(256) void k_attn(const bf16* __restrict__ Q, const bf16* __restrict__ KV,
                                              const bf16* __restrict__ KR, const bf16* __restrict__ VT,
                                              bf16* __restrict__ O) {
  __shared__ __align__(16) bf16 Ks[64 * 200];     // [kvpos][192+8]  25.0KB
  __shared__ __align__(16) bf16 Vt[128 * 72];     // [feat][64+8]    18.0KB
  __shared__ __align__(16) bf16 Ps[4 * 16 * 72];  // per-wave P       9.0KB
  int bid = blockIdx.x;
  int h = bid & 15, i = bid >> 4;
  int qb = (i < 16) ? i : 47 - i;
  int q0 = qb * 64;
  int tid = threadIdx.x, lane = tid & 63, w = tid >> 6;
  int l15 = lane & 15, l4 = lane >> 4;
  bf16* Pw = Ps + w * 16 * 72;
  const bf16* VTh = VT + (size_t)h * 128 * 2048;

  // Q fragments in registers
  bf16x8 aq[6];
  int qrow = q0 + w * 16 + l15;
#pragma unroll
  for (int ks = 0; ks < 6; ++ks)
    aq[ks] = *(const bf16x8*)&Q[(size_t)qrow * 3072 + h * 192 + ks * 32 + l4 * 8];

  // constant ones B-fragment (row n=0 of B = ones) for lsum-via-MFMA
  bf16x8 ones_b;
  {
    float ov = (l15 == 0) ? 1.0f : 0.0f;
#pragma unroll
    for (int j = 0; j < 8; ++j) ones_b[j] = (bf16)ov;
  }

  f32x4 oacc[8] = {};
  f32x4 o9 = {0.f, 0.f, 0.f, 0.f};  // running lsum per row (col 0 of ones-MFMA)
  float m[4] = {-1e30f, -1e30f, -1e30f, -1e30f};
  int nt = qb + 1;
  for (int t = 0; t < nt; ++t) {
    // stage K tile [64][192]: cols 0..127 = k_nope, 128..191 = k_rope
#pragma unroll
    for (int it = 0; it < 6; ++it) {
      int idx = it * 256 + tid;
      int r = idx / 24, gg = idx % 24;
      int p = t * 64 + r;
      int4 val;
      if (gg < 16) val = *(const int4*)&KV[(size_t)p * 4096 + h * 256 + gg * 8];
      else         val = *(const int4*)&KR[(size_t)p * 64 + (gg - 16) * 8];
      *(int4*)&Ks[r * 200 + gg * 8] = val;
    }
    // stage V^T tile [128 d][64 k] from VT (coalesced, vectorized)
#pragma unroll
    for (int it = 0; it < 4; ++it) {
      int idx = it * 256 + tid;
      int d = idx >> 3, c = idx & 7;
      *(int4*)&Vt[d * 72 + c * 8] = *(const int4*)&VTh[(size_t)d * 2048 + t * 64 + c * 8];
    }
    __syncthreads();  // A: tiles ready

    // S = Q @ K^T : 16x64 per wave
    f32x4 sacc[4] = {};
    __builtin_amdgcn_s_setprio(1);
#pragma unroll
    for (int ks = 0; ks < 6; ++ks)
#pragma unroll
      for (int n = 0; n < 4; ++n) {
        bf16x8 bk = *(const bf16x8*)&Ks[(n * 16 + l15) * 200 + ks * 32 + l4 * 8];
        sacc[n] = __builtin_amdgcn_mfma_f32_16x16x32_bf16(aq[ks], bk, sacc[n], 0, 0, 0);
      }
    __builtin_amdgcn_s_setprio(0);

    // scale (log2 domain) + causal mask (diagonal tile only)
    bool lastt = (t == nt - 1);
#pragma unroll
    for (int n = 0; n < 4; ++n)
#pragma unroll
      for (int r = 0; r < 4; ++r) {
        float v = sacc[n][r] * SCALE_LOG2E;
        if (lastt) {
          int col = t * 64 + n * 16 + l15;
          int rowg = q0 + w * 16 + l4 * 4 + r;
          if (col > rowg) v = -1e30f;
        }
        sacc[n][r] = v;
      }

    // row max
    float pmax[4];
#pragma unroll
    for (int r = 0; r < 4; ++r) {
      float mx = fmaxf(fmaxf(sacc[0][r], sacc[1][r]), fmaxf(sacc[2][r], sacc[3][r]));
      mx = fmaxf(mx, __shfl_xor(mx, 1));
      mx = fmaxf(mx, __shfl_xor(mx, 2));
      mx = fmaxf(mx, __shfl_xor(mx, 4));
      mx = fmaxf(mx, __shfl_xor(mx, 8));
      pmax[r] = mx;
    }
    // defer-max (T13): only rescale when the max moved by > 8 (in log2 domain)
    float need = 0.f;
#pragma unroll
    for (int r = 0; r < 4; ++r) need = fmaxf(need, pmax[r] - m[r]);
    if (__any(need > 8.0f)) {
#pragma unroll
      for (int r = 0; r < 4; ++r) {
        float mn = fmaxf(m[r], pmax[r]);
        float al = fexp2(m[r] - mn);
        m[r] = mn;
#pragma unroll
        for (int vf = 0; vf < 8; ++vf) oacc[vf][r] *= al;
        o9[r] *= al;
      }
    }

    // P = exp2(S - m) -> bf16 -> per-wave LDS
#pragma unroll
    for (int n = 0; n < 4; ++n)
#pragma unroll
      for (int r = 0; r < 4; ++r)
        Pw[(l4 * 4 + r) * 72 + n * 16 + l15] = (bf16)fexp2(sacc[n][r] - m[r]);

    // PV + lsum MFMAs (Pw is wave-private; Vt staged pre-barrier-A -> no barrier needed)
    __builtin_amdgcn_s_setprio(1);
#pragma unroll
    for (int ks = 0; ks < 2; ++ks) {
      bf16x8 ap = *(const bf16x8*)&Pw[l15 * 72 + ks * 32 + l4 * 8];
      o9 = __builtin_amdgcn_mfma_f32_16x16x32_bf16(ap, ones_b, o9, 0, 0, 0);
#pragma unroll
      for (int vf = 0; vf < 8; ++vf) {
        bf16x8 bv = *(const bf16x8*)&Vt[(vf * 16 + l15) * 72 + ks * 32 + l4 * 8];
        oacc[vf] = __builtin_amdgcn_mfma_f32_16x16x32_bf16(ap, bv, oacc[vf], 0, 0, 0);
      }
    }
    __builtin_amdgcn_s_setprio(0);
    __syncthreads();  // C: PV done -> next stage may overwrite Ks/Vt
  }

  // epilogue: lsum broadcast from col-0 lanes, normalize, store
#pragma unroll
  for (int r = 0; r < 4; ++r) {
    float ls = __shfl(o9[r], lane & 48);
    float inv = 1.0f / ls;
#pragma unroll
    for (int vf = 0; vf < 8; ++vf) {
      int rowg = q0 + w * 16 + l4 * 4 + r;
      int col = h * 128 + vf * 16 + l15;
      O[(size_t)rowg * 2048 + col] = (bf16)(oacc[vf][r] * inv);
    }
  }
}

extern "C" void kernel_launch(void* const* d_in, const int* in_sizes, int n_in,
                              void* d_out, int out_size, void* d_ws, size_t ws_size,
                              hipStream_t stream) {
  (void)in_sizes; (void)n_in; (void)out_size; (void)ws_size;
  const float* hidden = (const float*)d_in[0];
  const float* Wqa  = (const float*)d_in[2];
  const float* gqa  = (const float*)d_in[3];
  const float* Wqb  = (const float*)d_in[4];
  const float* Wkva = (const float*)d_in[5];
  const float* gkva = (const float*)d_in[6];
  const float* Wkvb = (const float*)d_in[7];
  const float* Wo   = (const float*)d_in[8];
  float* out = (float*)d_out;

  char* ws = (char*)d_ws;
  size_t off = 0;
  auto alloc = [&](size_t bytes) {
    char* p = ws + off;
    off += (bytes + 255) & ~(size_t)255;
    return p;
  };
  bf16* Xb     = (bf16*)alloc((size_t)SEQ * HIDDEN * 2);
  bf16* WqaT   = (bf16*)alloc((size_t)QL * HIDDEN * 2);
  bf16* WqbT   = (bf16*)alloc((size_t)3072 * QL * 2);
  bf16* WkvaT  = (bf16*)alloc((size_t)576 * HIDDEN * 2);
  bf16* WkvbT  = (bf16*)alloc((size_t)4096 * KVL * 2);
  bf16* WoT    = (bf16*)alloc((size_t)2048 * 2048 * 2);
  float* qa    = (float*)alloc((size_t)SEQ * QL * 4);
  float* kvc   = (float*)alloc((size_t)SEQ * 576 * 4);
  bf16* qc     = (bf16*)alloc((size_t)SEQ * QL * 2);
  bf16* kvn    = (bf16*)alloc((size_t)SEQ * KVL * 2);
  bf16* krope  = (bf16*)alloc((size_t)SEQ * 64 * 2);
  bf16* Qm     = (bf16*)alloc((size_t)SEQ * 3072 * 2);
  bf16* KVm    = (bf16*)alloc((size_t)SEQ * 4096 * 2);
  bf16* VTg    = (bf16*)alloc((size_t)NH * 128 * SEQ * 2);
  bf16* Om     = (bf16*)alloc((size_t)SEQ * 2048 * 2);

  k_prep<<<19072, 256, 0, stream>>>(hidden, Xb, Wqa, WqaT, Wqb, WqbT,
                                    Wkva, WkvaT, Wkvb, WkvbT, Wo, WoT);
  k_gemm_a<<<dim3(16, 17), 256, 0, stream>>>(Xb, WqaT, WkvaT, qa, kvc);
  k_rms_all<<<4096, 256, 0, stream>>>(qa, gqa, qc, kvc, gkva, kvn, krope);
  k_gemm_b<<<dim3(16, 56), 256, 0, stream>>>(qc, kvn, WqbT, WkvbT, Qm, KVm);
  k_vt<<<4096, 256, 0, stream>>>(KVm, VTg);
  k_attn<<<512, 256, 0, stream>>>(Qm, KVm, krope, VTg, Om);
  k_gemm<<<dim3(16, 16), 256, 0, stream>>>(Om, WoT, nullptr, out, 2048, 2048);
}